// Round 7
// baseline (2240.095 us; speedup 1.0000x reference)
//
#include <hip/hip_runtime.h>

typedef unsigned int u32;
typedef unsigned short u16;
typedef __attribute__((ext_vector_type(8))) short short8;
typedef __attribute__((ext_vector_type(4))) float floatx4;

#define L2E  1.44269504088896340736f
#define L2E2 2.88539008177792681472f

static __device__ __forceinline__ u16 f2bf(float f){
  u32 u = __float_as_uint(f);
  u = (u + 0x7FFFu + ((u >> 16) & 1u)) >> 16;
  return (u16)u;
}
static __device__ __forceinline__ float rcp_(float x){ return __builtin_amdgcn_rcpf(x); }
static __device__ __forceinline__ float exp2_(float x){ return __builtin_amdgcn_exp2f(x); }
static __device__ __forceinline__ float sigm2(float yh){ return rcp_(1.f + exp2_(-yh)); }   // log2e folded
static __device__ __forceinline__ float tanh2(float yh2){ return 1.f - 2.f*rcp_(1.f + exp2_(yh2)); } // 2*log2e folded

#define MFMA __builtin_amdgcn_mfma_f32_16x16x32_bf16

// ---- prep: weights -> slice-major MFMA B-frag order, bf16, log2e-prescaled ----
// (r5 layout, validated). slice s (units [s*16,s*16+16), all 4 gates):
// element (g,c,L,j) = W[g*128+s*16+(L&15)][c*32+(L>>4)*8+j] * scale(g).
// cell0: slice stride 8192. cell1: slice stride 16384, [Whh | Wih] per slice.
__global__ __launch_bounds__(256) void prep_weights(
    const float* eWhh0, const float* eWhh1, const float* eWih1,
    const float* dWhh0, const float* dWhh1, const float* dWih1,
    u16* wE0, u16* wE1, u16* wD0, u16* wD1)
{
  int idx = blockIdx.x * 256 + threadIdx.x;   // 6*65536
  int m = idx >> 16, e = idx & 65535;
  int j = e & 7, L = (e >> 3) & 63, c = (e >> 9) & 3, g = (e >> 11) & 3, s = (e >> 13) & 7;
  int row = g*128 + s*16 + (L & 15);
  int col = c*32 + ((L >> 4) * 8) + j;
  float scale = (g == 2) ? L2E2 : L2E;
  int frag = (g*4 + c)*512 + L*8 + j;
  const float* src; u16* dst; long off;
  switch(m){
    case 0: src = eWhh0; dst = wE0; off = (long)s*8192  + frag; break;
    case 1: src = eWhh1; dst = wE1; off = (long)s*16384 + frag; break;
    case 2: src = eWih1; dst = wE1; off = (long)s*16384 + 8192 + frag; break;
    case 3: src = dWhh0; dst = wD0; off = (long)s*8192  + frag; break;
    case 4: src = dWhh1; dst = wD1; off = (long)s*16384 + frag; break;
    default:src = dWih1; dst = wD1; off = (long)s*16384 + 8192 + frag; break;
  }
  dst[off] = f2bf(src[row*128 + col] * scale);
}

__global__ __launch_bounds__(256) void prep_small(
    const float* ebih0,const float* ebhh0,const float* ebih1,const float* ebhh1,
    const float* dbih0,const float* dbhh0,const float* dbih1,const float* dbhh1,
    const float* eWih0,const float* dWih0, float* biasAll, float* wxAll)
{
  int i = blockIdx.x*256 + threadIdx.x;    // 4096
  if (i < 2048){
    int l = i >> 9, n = i & 511, g = (n >> 7) & 3;
    const float* a = l==0?ebih0: l==1?ebih1: l==2?dbih0: dbih1;
    const float* b = l==0?ebhh0: l==1?ebhh1: l==2?dbhh0: dbhh1;
    biasAll[i] = (a[n] + b[n]) * ((g==2)? L2E2 : L2E);
  } else {
    int k = i - 2048;                       // 2 x 1024
    int l = k >> 10, e2 = k & 1023, n = e2 >> 1, g = (n >> 7) & 3;
    const float* wsrc = l ? dWih0 : eWih0;
    wxAll[k] = wsrc[e2] * ((g==2)? L2E2 : L2E);
  }
}

// =======================================================================
// 256 blocks x 512 thr. 8 waves = M-split 2 (mh=w&1: 64 samples, mtiles
// mh*4..mh*4+3) x N-split 4 (grp=w>>1: 32 units = slices grp*2, grp*2+1).
// Weights read per-use directly from global (L2-resident) into registers.
// h slabs double-buffered in LDS (read cur = tt&1, write nxt) so A-frags
// stream per c-chunk with only TWO barriers per step:
//   barrier1: h0_new complete -> cell1 may read it
//   barrier2: h1_new complete (+ FC partials in fcp) -> next step / xc
// c-state in VGPRs for the whole chunk; FC feedback in registers via fcp.
// =======================================================================
template<bool DEC>
static __device__ __forceinline__ void step2(
    int grp, int mh, int lane, int n4, int q, int m0, int t, int tt,
    u16* h0s, u16* h1s, float* fcp,
    const float* sB, const float* sWx, const float* sFc,
    const u16* wC0, const u16* wC1,
    float2 (&xc)[4][4],
    floatx4 (&c0a)[4][2], floatx4 (&c1a)[4][2],
    float* __restrict__ out)
{
  const int cur = tt & 1, nxt = cur ^ 1;
  const u16* h0r = h0s + cur*16384;
  u16*       h0w = h0s + nxt*16384;
  const u16* h1r = h1s + cur*16384;
  u16*       h1w = h1s + nxt*16384;
  const int MT0 = mh*4;

  // ---------------- cell 0: slices grp*2, grp*2+1 ----------------
  #pragma unroll 1
  for (int sl = 0; sl < 2; sl++){
    const int s = grp*2 + sl;
    floatx4 acc[4][4];
    #pragma unroll
    for (int g = 0; g < 4; g++){
      float bi = sB[g*128 + s*16 + n4];
      float2 wv = *(const float2*)(sWx + (g*128 + s*16 + n4)*2);
      #pragma unroll
      for (int mt = 0; mt < 4; mt++)
        #pragma unroll
        for (int r = 0; r < 4; r++)
          acc[g][mt][r] = fmaf(xc[mt][r].y, wv.y, fmaf(xc[mt][r].x, wv.x, bi));
    }
    const u16* wb = wC0 + s*8192;
    #pragma unroll
    for (int c = 0; c < 4; c++){
      short8 a_c[4], b_c[4];
      #pragma unroll
      for (int mt = 0; mt < 4; mt++)
        a_c[mt] = *(const short8*)(h0r + ((MT0+mt)*4 + c)*512 + lane*8);
      #pragma unroll
      for (int g = 0; g < 4; g++)
        b_c[g] = *(const short8*)(wb + (g*4 + c)*512 + lane*8);
      #pragma unroll
      for (int g = 0; g < 4; g++)
        #pragma unroll
        for (int mt = 0; mt < 4; mt++)
          acc[g][mt] = MFMA(a_c[mt], b_c[g], acc[g][mt], 0,0,0);
    }
    #pragma unroll
    for (int mt = 0; mt < 4; mt++){
      const int hb = ((MT0+mt)*4 + (s>>1))*512 + ((s&1)*2 + (n4>>3))*128 + q*32 + (n4&7);
      floatx4 cc = c0a[mt][sl], cn;
      #pragma unroll
      for (int r = 0; r < 4; r++){
        float ig = sigm2(acc[0][mt][r]);
        float fg = sigm2(acc[1][mt][r]);
        float gg = tanh2(acc[2][mt][r]);
        float cv = fmaf(fg, cc[r], ig*gg);
        float og = sigm2(acc[3][mt][r]);
        float hv = og * (1.f - 2.f*rcp_(1.f + exp2_(L2E2*cv)));
        cn[r] = cv;
        h0w[hb + r*8] = f2bf(hv);
      }
      c0a[mt][sl] = cn;
    }
  }
  __syncthreads();   // barrier 1: h0_new visible

  // ---------------- cell 1: K=256 ([h1_old | h0_new]) ----------------
  float p[4][4][2];
  if (DEC){
    #pragma unroll
    for (int mt = 0; mt < 4; mt++)
      #pragma unroll
      for (int r = 0; r < 4; r++){ p[mt][r][0] = 0.f; p[mt][r][1] = 0.f; }
  }
  #pragma unroll 1
  for (int sl = 0; sl < 2; sl++){
    const int s = grp*2 + sl;
    floatx4 acc[4][4];
    #pragma unroll
    for (int g = 0; g < 4; g++){
      float bi = sB[512 + g*128 + s*16 + n4];
      #pragma unroll
      for (int mt = 0; mt < 4; mt++)
        #pragma unroll
        for (int r = 0; r < 4; r++) acc[g][mt][r] = bi;
    }
    const u16* wb = wC1 + s*16384;
    #pragma unroll
    for (int c = 0; c < 4; c++){
      short8 a1c[4], anc[4], bh[4], bx[4];
      #pragma unroll
      for (int mt = 0; mt < 4; mt++){
        a1c[mt] = *(const short8*)(h1r + ((MT0+mt)*4 + c)*512 + lane*8);
        anc[mt] = *(const short8*)(h0w + ((MT0+mt)*4 + c)*512 + lane*8);
      }
      #pragma unroll
      for (int g = 0; g < 4; g++){
        bh[g] = *(const short8*)(wb + (g*4 + c)*512 + lane*8);
        bx[g] = *(const short8*)(wb + 8192 + (g*4 + c)*512 + lane*8);
      }
      #pragma unroll
      for (int g = 0; g < 4; g++)
        #pragma unroll
        for (int mt = 0; mt < 4; mt++){
          acc[g][mt] = MFMA(a1c[mt], bh[g], acc[g][mt], 0,0,0);
          acc[g][mt] = MFMA(anc[mt], bx[g], acc[g][mt], 0,0,0);
        }
    }
    float f0 = 0.f, f1 = 0.f;
    if (DEC){ f0 = sFc[s*16 + n4]; f1 = sFc[128 + s*16 + n4]; }
    #pragma unroll
    for (int mt = 0; mt < 4; mt++){
      const int hb = ((MT0+mt)*4 + (s>>1))*512 + ((s&1)*2 + (n4>>3))*128 + q*32 + (n4&7);
      floatx4 cc = c1a[mt][sl], cn;
      #pragma unroll
      for (int r = 0; r < 4; r++){
        float ig = sigm2(acc[0][mt][r]);
        float fg = sigm2(acc[1][mt][r]);
        float gg = tanh2(acc[2][mt][r]);
        float cv = fmaf(fg, cc[r], ig*gg);
        float og = sigm2(acc[3][mt][r]);
        float hv = og * (1.f - 2.f*rcp_(1.f + exp2_(L2E2*cv)));
        cn[r] = cv;
        h1w[hb + r*8] = f2bf(hv);
        if (DEC){
          p[mt][r][0] = fmaf(hv, f0, p[mt][r][0]);
          p[mt][r][1] = fmaf(hv, f1, p[mt][r][1]);
        }
      }
      c1a[mt][sl] = cn;
    }
  }
  if (DEC){
    #pragma unroll
    for (int off = 1; off < 16; off <<= 1)
      #pragma unroll
      for (int mt = 0; mt < 4; mt++)
        #pragma unroll
        for (int r = 0; r < 4; r++){
          p[mt][r][0] += __shfl_xor(p[mt][r][0], off);
          p[mt][r][1] += __shfl_xor(p[mt][r][1], off);
        }
    if (n4 == 0){
      #pragma unroll
      for (int mt = 0; mt < 4; mt++)
        #pragma unroll
        for (int r = 0; r < 4; r++){
          const int base = ((MT0+mt)*16 + q*4 + r)*8 + grp*2;
          fcp[base + 0] = p[mt][r][0];
          fcp[base + 1] = p[mt][r][1];
        }
    }
  }
  __syncthreads();   // barrier 2: h1_new + fcp visible

  if (DEC){
    const float fb0 = sFc[256], fb1 = sFc[257];
    #pragma unroll
    for (int mt = 0; mt < 4; mt++)
      #pragma unroll
      for (int r = 0; r < 4; r++){
        const int base = ((MT0+mt)*16 + q*4 + r)*8;
        float4 v0 = *(const float4*)(fcp + base);
        float4 v1 = *(const float4*)(fcp + base + 4);
        float2 pv;
        pv.x = v0.x + v0.z + v1.x + v1.z + fb0;
        pv.y = v0.y + v0.w + v1.y + v1.w + fb1;
        xc[mt][r] = pv;
        if (grp == 0 && n4 == 0)
          *(float2*)(out + (long)(m0 + (MT0+mt)*16 + q*4 + r)*90 + (t - 20)*2) = pv;
      }
  }
}

__global__ __launch_bounds__(512, 2) void enc_all(
    const float* __restrict__ in_seq,
    const u16* __restrict__ wE0, const u16* __restrict__ wE1,
    const float* __restrict__ biasAll, const float* __restrict__ wxAll,
    u16* __restrict__ gH0, u16* __restrict__ gH1,
    float* __restrict__ gC0, float* __restrict__ gC1)
{
  __shared__ u16 h0s[32768];   // 2 x 32KB dbuf
  __shared__ u16 h1s[32768];
  __shared__ float sB[1024];
  __shared__ float sWx[1024];

  const int tid = threadIdx.x, lane = tid & 63, w = tid >> 6;
  const int grp = w >> 1, mh = w & 1;
  const int n4 = lane & 15, q = lane >> 4;
  const int m0 = blockIdx.x * 128;
  const long hoff = (long)blockIdx.x * 16384;
  const long cbase = (long)blockIdx.x * 512 + tid;

  for (int i = tid; i < 1024; i += 512){ sB[i] = biasAll[i]; sWx[i] = wxAll[i]; }
  { u32* z0 = (u32*)h0s; u32* z1 = (u32*)h1s;
    for (int i = tid; i < 8192; i += 512){ z0[i] = 0u; z1[i] = 0u; } }  // buf0 only

  floatx4 c0a[4][2], c1a[4][2];
  const floatx4 z4 = {0.f,0.f,0.f,0.f};
  #pragma unroll
  for (int mt = 0; mt < 4; mt++)
    #pragma unroll
    for (int sl = 0; sl < 2; sl++){ c0a[mt][sl] = z4; c1a[mt][sl] = z4; }
  __syncthreads();

  float2 xc[4][4];
  #pragma unroll 1
  for (int tt = 0; tt < 20; tt++){
    #pragma unroll
    for (int mt = 0; mt < 4; mt++)
      #pragma unroll
      for (int r = 0; r < 4; r++)
        xc[mt][r] = *(const float2*)(in_seq + (long)(m0 + (mh*4+mt)*16 + q*4 + r)*40 + tt*2);
    step2<false>(grp, mh, lane, n4, q, m0, tt, tt, h0s, h1s, (float*)nullptr,
                 sB, sWx, (const float*)nullptr, wE0, wE1, xc, c0a, c1a, (float*)nullptr);
  }

  // flush: after 20 steps state is in buf[20&1] = buf0
  { const uint4* s0 = (const uint4*)h0s; const uint4* s1 = (const uint4*)h1s;
    uint4* d0 = (uint4*)(gH0 + hoff); uint4* d1 = (uint4*)(gH1 + hoff);
    for (int i = tid; i < 2048; i += 512){ d0[i] = s0[i]; d1[i] = s1[i]; } }
  { floatx4* pc0 = (floatx4*)gC0; floatx4* pc1 = (floatx4*)gC1;
    #pragma unroll
    for (int mt = 0; mt < 4; mt++)
      #pragma unroll
      for (int sl = 0; sl < 2; sl++){
        pc0[(long)(mt*2+sl)*131072 + cbase] = c0a[mt][sl];
        pc1[(long)(mt*2+sl)*131072 + cbase] = c1a[mt][sl];
      } }
}

__global__ __launch_bounds__(512, 2) void dec_chunk(
    const float* __restrict__ in_seq,
    const u16* __restrict__ wD0, const u16* __restrict__ wD1,
    const float* __restrict__ biasD, const float* __restrict__ wxD,
    const float* __restrict__ fcW, const float* __restrict__ fcb,
    u16* __restrict__ gH0, u16* __restrict__ gH1,
    float* __restrict__ gC0, float* __restrict__ gC1,
    float* __restrict__ gPred, float* __restrict__ out,
    int t0, int K, int first)
{
  __shared__ u16 h0s[32768];
  __shared__ u16 h1s[32768];
  __shared__ float sB[1024];
  __shared__ float sWx[1024];
  __shared__ float sFc[260];
  __shared__ float fcp[1024];

  const int tid = threadIdx.x, lane = tid & 63, w = tid >> 6;
  const int grp = w >> 1, mh = w & 1;
  const int n4 = lane & 15, q = lane >> 4;
  const int m0 = blockIdx.x * 128;
  const long hoff = (long)blockIdx.x * 16384;
  const long cbase = (long)blockIdx.x * 512 + tid;

  for (int i = tid; i < 1024; i += 512){ sB[i] = biasD[i]; sWx[i] = wxD[i]; }
  if (tid < 258) sFc[tid] = (tid < 256) ? fcW[tid] : fcb[tid-256];

  floatx4 c0a[4][2], c1a[4][2];
  { uint4* d0 = (uint4*)h0s; uint4* d1 = (uint4*)h1s;     // into buf0
    const uint4* s0 = (const uint4*)(gH0 + hoff);
    const uint4* s1 = (const uint4*)(gH1 + hoff);
    for (int i = tid; i < 2048; i += 512){ d0[i] = s0[i]; d1[i] = s1[i]; }
    const floatx4* pc0 = (const floatx4*)gC0;
    const floatx4* pc1 = (const floatx4*)gC1;
    #pragma unroll
    for (int mt = 0; mt < 4; mt++)
      #pragma unroll
      for (int sl = 0; sl < 2; sl++){
        c0a[mt][sl] = pc0[(long)(mt*2+sl)*131072 + cbase];
        c1a[mt][sl] = pc1[(long)(mt*2+sl)*131072 + cbase];
      } }

  float2 xc[4][4];
  #pragma unroll
  for (int mt = 0; mt < 4; mt++)
    #pragma unroll
    for (int r = 0; r < 4; r++){
      const long mm = m0 + (mh*4+mt)*16 + q*4 + r;
      xc[mt][r] = first ? *(const float2*)(in_seq + mm*40 + 38)
                        : *(const float2*)(gPred + mm*2);
    }
  __syncthreads();

  #pragma unroll 1
  for (int tt = 0; tt < K; tt++){
    step2<true>(grp, mh, lane, n4, q, m0, t0 + tt, tt, h0s, h1s, fcp,
                sB, sWx, sFc, wD0, wD1, xc, c0a, c1a, out);
  }

  // flush from buf[K&1]
  { const int fo = (K & 1) * 16384;
    const uint4* s0 = (const uint4*)(h0s + fo); const uint4* s1 = (const uint4*)(h1s + fo);
    uint4* d0 = (uint4*)(gH0 + hoff); uint4* d1 = (uint4*)(gH1 + hoff);
    for (int i = tid; i < 2048; i += 512){ d0[i] = s0[i]; d1[i] = s1[i]; } }
  { floatx4* pc0 = (floatx4*)gC0; floatx4* pc1 = (floatx4*)gC1;
    #pragma unroll
    for (int mt = 0; mt < 4; mt++)
      #pragma unroll
      for (int sl = 0; sl < 2; sl++){
        pc0[(long)(mt*2+sl)*131072 + cbase] = c0a[mt][sl];
        pc1[(long)(mt*2+sl)*131072 + cbase] = c1a[mt][sl];
      } }
  if (grp == 0 && n4 == 0){
    #pragma unroll
    for (int mt = 0; mt < 4; mt++)
      #pragma unroll
      for (int r = 0; r < 4; r++)
        *(float2*)(gPred + (long)(m0 + (mh*4+mt)*16 + q*4 + r)*2) = xc[mt][r];
  }
}

// ---------------- host ----------------
extern "C" void kernel_launch(void* const* d_in, const int* in_sizes, int n_in,
                              void* d_out, int out_size, void* d_ws, size_t ws_size,
                              hipStream_t stream)
{
  const float* in_seq = (const float*)d_in[0];
  const float* eWih0 = (const float*)d_in[1];
  const float* eWhh0 = (const float*)d_in[2];
  const float* ebih0 = (const float*)d_in[3];
  const float* ebhh0 = (const float*)d_in[4];
  const float* eWih1 = (const float*)d_in[5];
  const float* eWhh1 = (const float*)d_in[6];
  const float* ebih1 = (const float*)d_in[7];
  const float* ebhh1 = (const float*)d_in[8];
  const float* dWih0 = (const float*)d_in[9];
  const float* dWhh0 = (const float*)d_in[10];
  const float* dbih0 = (const float*)d_in[11];
  const float* dbhh0 = (const float*)d_in[12];
  const float* dWih1 = (const float*)d_in[13];
  const float* dWhh1 = (const float*)d_in[14];
  const float* dbih1 = (const float*)d_in[15];
  const float* dbhh1 = (const float*)d_in[16];
  const float* fcW   = (const float*)d_in[17];
  const float* fcb   = (const float*)d_in[18];
  float* out = (float*)d_out;
  char* ws = (char*)d_ws;

  u16* wE0 = (u16*)(ws + 0);                   // 128 KB
  u16* wE1 = (u16*)(ws + 131072);              // 256 KB
  u16* wD0 = (u16*)(ws + 393216);              // 128 KB
  u16* wD1 = (u16*)(ws + 524288);              // 256 KB
  float* biasAll = (float*)(ws + 786432);      // 8 KB
  float* wxAll   = (float*)(ws + 794624);      // 8 KB
  u16* gH0   = (u16*)(ws + 1048576);           // 8 MB
  u16* gH1   = (u16*)(ws + 9437184);           // 8 MB
  float* gC0 = (float*)(ws + 17825792);        // 16 MB
  float* gC1 = (float*)(ws + 34603008);        // 16 MB
  float* gPred = (float*)(ws + 51380224);      // 256 KB

  hipLaunchKernelGGL(prep_weights, dim3(1536), dim3(256), 0, stream,
                     eWhh0, eWhh1, eWih1, dWhh0, dWhh1, dWih1,
                     wE0, wE1, wD0, wD1);
  hipLaunchKernelGGL(prep_small, dim3(16), dim3(256), 0, stream,
                     ebih0, ebhh0, ebih1, ebhh1, dbih0, dbhh0, dbih1, dbhh1,
                     eWih0, dWih0, biasAll, wxAll);

  hipLaunchKernelGGL(enc_all, dim3(256), dim3(512), 0, stream,
                     in_seq, (const u16*)wE0, (const u16*)wE1,
                     (const float*)biasAll, (const float*)wxAll,
                     gH0, gH1, gC0, gC1);

  for (int t0 = 20; t0 < 65; t0 += 15)
    hipLaunchKernelGGL(dec_chunk, dim3(256), dim3(512), 0, stream,
                       in_seq, (const u16*)wD0, (const u16*)wD1,
                       (const float*)(biasAll + 1024), (const float*)(wxAll + 1024),
                       fcW, fcb, gH0, gH1, gC0, gC1, gPred, out,
                       t0, 15, (t0 == 20) ? 1 : 0);
}